// Round 2
// baseline (295.299 us; speedup 1.0000x reference)
//
#include <hip/hip_runtime.h>
#include <hip/hip_bf16.h>
#include <stdint.h>

// Problem: B=4, S=2048, D=1024. fp32 in, fp32 out.
#define BB 4
#define SS 2048
#define DD 1024

typedef __attribute__((ext_vector_type(4))) float f32x4;
typedef __attribute__((ext_vector_type(8))) __bf16 bf16x8;

typedef const __attribute__((address_space(1))) void* gptr_t;
typedef __attribute__((address_space(3))) void* lptr_t;

__device__ __forceinline__ void load_lds16(const void* g, void* l) {
  // async global->LDS, 16B per lane; LDS dest = wave-uniform base + lane*16
  __builtin_amdgcn_global_load_lds((gptr_t)g, (lptr_t)l, 16, 0, 0);
}

__device__ __forceinline__ unsigned short f2bf(float x) {
  union { float f; uint32_t u; } v; v.f = x;
  uint32_t u = v.u;
  return (unsigned short)((u + 0x7FFFu + ((u >> 16) & 1u)) >> 16); // RNE
}
__device__ __forceinline__ float bf2f(unsigned short h) {
  union { uint32_t u; float f; } v; v.u = ((uint32_t)h) << 16; return v.f;
}

// ---------------- fp32 -> bf16 convert: x (grid-stride) ----------------
__global__ __launch_bounds__(256) void convert_x(
    const float* __restrict__ in, unsigned short* __restrict__ out, int n4) {
  for (int i = blockIdx.x * 256 + threadIdx.x; i < n4; i += gridDim.x * 256) {
    float4 v = ((const float4*)in)[i];
    ushort4 o;
    o.x = f2bf(v.x); o.y = f2bf(v.y); o.z = f2bf(v.z); o.w = f2bf(v.w);
    ((ushort4*)out)[i] = o;
  }
}

// ---------------- fp32 -> bf16 convert: the 3 weight matrices, one launch ----
__global__ __launch_bounds__(256) void convert_w(
    const float* __restrict__ wq, const float* __restrict__ wk,
    const float* __restrict__ wv, unsigned short* __restrict__ wcat) {
  const int n4 = DD * DD / 4;  // per matrix
  int i = blockIdx.x * 256 + threadIdx.x;          // 0 .. 3*n4-1
  const int which = i / n4, j = i - which * n4;
  const float* src = (which == 0) ? wq : ((which == 1) ? wk : wv);
  float4 v = ((const float4*)src)[j];
  ushort4 o;
  o.x = f2bf(v.x); o.y = f2bf(v.y); o.z = f2bf(v.z); o.w = f2bf(v.w);
  ((ushort4*)(wcat + (size_t)which * DD * DD))[j] = o;
}

// ---------------- GEMM core: C[128x128] = A[M,K] @ Bt[N,K]^T ----------------
// m97 structure: 256 thr (4 waves, 2x2), BK=32, global_load_lds w=16,
// ds_read_b128 frags, mfma_f32_16x16x32_bf16, 2 barriers / K-step.
__device__ __forceinline__ void gemm_core_128(
    const unsigned short* __restrict__ A, const unsigned short* __restrict__ Bt,
    int K, int lda, int ldb, int row0, int col0,
    unsigned short* As, unsigned short* Bs, f32x4 acc[4][4]) {
  const int tid  = threadIdx.x;
  const int lane = tid & 63;
  const int wave = tid >> 6;
  const int wm = wave >> 1, wn = wave & 1;

#pragma unroll
  for (int i = 0; i < 4; ++i)
#pragma unroll
    for (int j = 0; j < 4; ++j) acc[i][j] = (f32x4)(0.f);

  // staging: 8 chunks of 16 rows x 32 cols per tile; wave w owns chunks w, w+4
  const unsigned short* aS0 = A  + (size_t)(row0 + wave * 16 + (lane >> 2)) * lda + (lane & 3) * 8;
  const unsigned short* aS1 = aS0 + (size_t)64 * lda;
  const unsigned short* bS0 = Bt + (size_t)(col0 + wave * 16 + (lane >> 2)) * ldb + (lane & 3) * 8;
  const unsigned short* bS1 = bS0 + (size_t)64 * ldb;
  unsigned short* lA0 = As + wave * 512;
  unsigned short* lA1 = As + (wave + 4) * 512;
  unsigned short* lB0 = Bs + wave * 512;
  unsigned short* lB1 = Bs + (wave + 4) * 512;

  const unsigned short* arow = As + ((wm * 64 + (lane & 15)) * 32) + (lane >> 4) * 8;
  const unsigned short* brow = Bs + ((wn * 64 + (lane & 15)) * 32) + (lane >> 4) * 8;

  for (int k0 = 0; k0 < K; k0 += 32) {
    load_lds16(aS0 + k0, lA0);
    load_lds16(aS1 + k0, lA1);
    load_lds16(bS0 + k0, lB0);
    load_lds16(bS1 + k0, lB1);
    __syncthreads();  // drains vmcnt -> tiles ready

    bf16x8 af[4], bf[4];
#pragma unroll
    for (int fm = 0; fm < 4; ++fm) af[fm] = *(const bf16x8*)(arow + fm * 512);
#pragma unroll
    for (int fn = 0; fn < 4; ++fn) bf[fn] = *(const bf16x8*)(brow + fn * 512);
#pragma unroll
    for (int fm = 0; fm < 4; ++fm)
#pragma unroll
      for (int fn = 0; fn < 4; ++fn)
        acc[fm][fn] = __builtin_amdgcn_mfma_f32_16x16x32_bf16(af[fm], bf[fn], acc[fm][fn], 0, 0, 0);
    __syncthreads();  // before next stage overwrites LDS
  }
}

// ---------------- projection GEMM: [8192,1024] @ Wcat[3072,1024]^T ----------------
// Wcat rows: [0,1024)=W_Q, [1024,2048)=W_K, [2048,3072)=W_V  (C = x @ W^T)
__global__ __launch_bounds__(256) void proj_gemm(
    const unsigned short* __restrict__ xb, const unsigned short* __restrict__ wcat,
    unsigned short* __restrict__ q, unsigned short* __restrict__ kk, unsigned short* __restrict__ vv) {
  __shared__ __align__(16) unsigned short As[128 * 32];
  __shared__ __align__(16) unsigned short Bs[128 * 32];
  f32x4 acc[4][4];
  const int bm = blockIdx.y, bn = blockIdx.x;
  gemm_core_128(xb, wcat, 1024, 1024, 1024, bm * 128, bn * 128, As, Bs, acc);

  const int tid = threadIdx.x, lane = tid & 63, wave = tid >> 6;
  const int wm = wave >> 1, wn = wave & 1;
  const int which = bn >> 3;  // 0:q 1:k 2:v (block col range is within one output)
  unsigned short* dst = (which == 0) ? q : ((which == 1) ? kk : vv);
  const int cb = (bn & 7) * 128 + wn * 64 + (lane & 15);
  const int rb = bm * 128 + wm * 64 + (lane >> 4) * 4;
#pragma unroll
  for (int fm = 0; fm < 4; ++fm)
#pragma unroll
    for (int i = 0; i < 4; ++i) {
      const size_t rowoff = (size_t)(rb + fm * 16 + i) * 1024;  // r = b*2048+s
#pragma unroll
      for (int fn = 0; fn < 4; ++fn)
        dst[rowoff + cb + fn * 16] = f2bf(acc[fm][fn][i]);
    }
}

// ---------------- K -> Mt (reshape folded transpose) ----------------
// scores = Q @ K_r with K_r[b][p][q] = K[b][2p+(q>=1024)][q%1024]
// We build Mt[b][j][p] = K_r[b][p][j] so score GEMM is C = Q @ Mt^T.
// Mt[b][delta*1024 + j][i] = K[b][2i+delta][j]
__global__ __launch_bounds__(256) void k_to_mt(
    const unsigned short* __restrict__ k, unsigned short* __restrict__ mt) {
  const int z = blockIdx.z, b = z >> 1, delta = z & 1;
  const unsigned short* kb = k + (size_t)b * SS * DD + (size_t)delta * DD;  // Kd[i][j], ld=2048
  unsigned short* mtb = mt + (size_t)b * SS * DD + (size_t)delta * DD * DD; // [1024][1024]
  __shared__ unsigned short tile[32][33];
  const int tx = threadIdx.x, ty = threadIdx.y;
  const int i0 = blockIdx.x * 32, j0 = blockIdx.y * 32;
#pragma unroll
  for (int yy = ty; yy < 32; yy += 8)
    tile[yy][tx] = kb[(size_t)(i0 + yy) * 2048 + j0 + tx];
  __syncthreads();
#pragma unroll
  for (int yy = ty; yy < 32; yy += 8)
    mtb[(size_t)(j0 + yy) * 1024 + i0 + tx] = tile[tx][yy];
}

// ---------------- V -> Vt ----------------
__global__ __launch_bounds__(256) void v_to_vt(
    const unsigned short* __restrict__ v, unsigned short* __restrict__ vt) {
  const int b = blockIdx.z;
  const unsigned short* vb = v + (size_t)b * SS * DD;   // V[k][n], ld=1024
  unsigned short* vtb = vt + (size_t)b * DD * SS;       // Vt[n][k], ld=2048
  __shared__ unsigned short tile[32][33];
  const int tx = threadIdx.x, ty = threadIdx.y;
  const int k0 = blockIdx.x * 32, n0 = blockIdx.y * 32;
#pragma unroll
  for (int yy = ty; yy < 32; yy += 8)
    tile[yy][tx] = vb[(size_t)(k0 + yy) * 1024 + n0 + tx];
  __syncthreads();
#pragma unroll
  for (int yy = ty; yy < 32; yy += 8)
    vtb[(size_t)(n0 + yy) * 2048 + k0 + tx] = tile[tx][yy];
}

// ---------------- scores GEMM: Q[2048,1024] @ Mt[2048,1024]^T, scale 1/1024, bf16 out ----
__global__ __launch_bounds__(256) void score_gemm(
    const unsigned short* __restrict__ q, const unsigned short* __restrict__ mt,
    unsigned short* __restrict__ sc) {
  __shared__ __align__(16) unsigned short As[128 * 32];
  __shared__ __align__(16) unsigned short Bs[128 * 32];
  f32x4 acc[4][4];
  const int b = blockIdx.z;
  gemm_core_128(q + (size_t)b * SS * DD, mt + (size_t)b * SS * DD,
                1024, 1024, 1024, blockIdx.y * 128, blockIdx.x * 128, As, Bs, acc);
  unsigned short* out = sc + (size_t)b * SS * SS;
  const int tid = threadIdx.x, lane = tid & 63, wave = tid >> 6;
  const int wm = wave >> 1, wn = wave & 1;
  const int cb = blockIdx.x * 128 + wn * 64 + (lane & 15);
  const int rb = blockIdx.y * 128 + wm * 64 + (lane >> 4) * 4;
  const float scale = 1.0f / 1024.0f;
#pragma unroll
  for (int fm = 0; fm < 4; ++fm)
#pragma unroll
    for (int i = 0; i < 4; ++i) {
      const size_t rowoff = (size_t)(rb + fm * 16 + i) * 2048;
#pragma unroll
      for (int fn = 0; fn < 4; ++fn)
        out[rowoff + cb + fn * 16] = f2bf(acc[fm][fn][i] * scale);
    }
}

// ---------------- row softmax IN-PLACE: bf16 [8192][2048] ----------------
// Each block owns one row; reads the whole row into registers before any
// write, so in-place is race-free.
__global__ __launch_bounds__(256) void softmax_kernel(unsigned short* __restrict__ sc) {
  const size_t row = blockIdx.x;
  unsigned short* io = sc + row * 2048;
  const int t = threadIdx.x;
  ushort4 u0 = ((const ushort4*)io)[t];
  ushort4 u1 = ((const ushort4*)io)[t + 256];
  float v[8];
  v[0] = bf2f(u0.x); v[1] = bf2f(u0.y); v[2] = bf2f(u0.z); v[3] = bf2f(u0.w);
  v[4] = bf2f(u1.x); v[5] = bf2f(u1.y); v[6] = bf2f(u1.z); v[7] = bf2f(u1.w);
  float m = v[0];
#pragma unroll
  for (int j = 1; j < 8; ++j) m = fmaxf(m, v[j]);
#pragma unroll
  for (int off = 32; off > 0; off >>= 1) m = fmaxf(m, __shfl_xor(m, off));
  __shared__ float redm[4], reds[4];
  const int w = t >> 6;
  if ((t & 63) == 0) redm[w] = m;
  __syncthreads();
  m = fmaxf(fmaxf(redm[0], redm[1]), fmaxf(redm[2], redm[3]));
  float s = 0.f;
#pragma unroll
  for (int j = 0; j < 8; ++j) { v[j] = __expf(v[j] - m); s += v[j]; }
#pragma unroll
  for (int off = 32; off > 0; off >>= 1) s += __shfl_xor(s, off);
  if ((t & 63) == 0) reds[w] = s;
  __syncthreads();
  const float inv = 1.0f / (reds[0] + reds[1] + reds[2] + reds[3]);
  ushort4 o0, o1;
  o0.x = f2bf(v[0] * inv); o0.y = f2bf(v[1] * inv); o0.z = f2bf(v[2] * inv); o0.w = f2bf(v[3] * inv);
  o1.x = f2bf(v[4] * inv); o1.y = f2bf(v[5] * inv); o1.z = f2bf(v[6] * inv); o1.w = f2bf(v[7] * inv);
  ((ushort4*)io)[t] = o0;
  ((ushort4*)io)[t + 256] = o1;
}

// ---------------- PV GEMM: P[2048,2048] @ Vt[1024,2048]^T -> fp32 out ----------------
__global__ __launch_bounds__(256) void pv_gemm(
    const unsigned short* __restrict__ p, const unsigned short* __restrict__ vt,
    float* __restrict__ out) {
  __shared__ __align__(16) unsigned short As[128 * 32];
  __shared__ __align__(16) unsigned short Bs[128 * 32];
  f32x4 acc[4][4];
  const int b = blockIdx.z;
  gemm_core_128(p + (size_t)b * SS * SS, vt + (size_t)b * DD * SS,
                2048, 2048, 2048, blockIdx.y * 128, blockIdx.x * 128, As, Bs, acc);
  float* ob = out + (size_t)b * SS * DD;
  const int tid = threadIdx.x, lane = tid & 63, wave = tid >> 6;
  const int wm = wave >> 1, wn = wave & 1;
  const int cb = blockIdx.x * 128 + wn * 64 + (lane & 15);
  const int rb = blockIdx.y * 128 + wm * 64 + (lane >> 4) * 4;
#pragma unroll
  for (int fm = 0; fm < 4; ++fm)
#pragma unroll
    for (int i = 0; i < 4; ++i) {
      const size_t rowoff = (size_t)(rb + fm * 16 + i) * 1024;
#pragma unroll
      for (int fn = 0; fn < 4; ++fn)
        ob[rowoff + cb + fn * 16] = acc[fm][fn][i];
    }
}

extern "C" void kernel_launch(void* const* d_in, const int* in_sizes, int n_in,
                              void* d_out, int out_size, void* d_ws, size_t ws_size,
                              hipStream_t stream) {
  const float* x  = (const float*)d_in[0];
  const float* wq = (const float*)d_in[1];
  const float* wk = (const float*)d_in[2];
  const float* wv = (const float*)d_in[3];
  float* out = (float*)d_out;
  uint8_t* ws = (uint8_t*)d_ws;

  const size_t MB = 1u << 20;
  unsigned short* xb   = (unsigned short*)(ws);               // 16 MB  [8192][1024]
  unsigned short* wcat = (unsigned short*)(ws + 16 * MB);     //  6 MB  [3072][1024]
  unsigned short* q    = (unsigned short*)(ws + 22 * MB);     // 16 MB
  unsigned short* kk   = (unsigned short*)(ws + 38 * MB);     // 16 MB
  unsigned short* vv   = (unsigned short*)(ws + 54 * MB);     // 16 MB
  unsigned short* mt   = (unsigned short*)(ws + 70 * MB);     // 16 MB  [b][2048][1024]
  unsigned short* vt   = (unsigned short*)(ws + 86 * MB);     // 16 MB  [b][1024][2048]
  unsigned short* sc   = (unsigned short*)(ws + 102 * MB);    // 32 MB  [b][2048][2048] (softmax in-place)
                                                              // -> 134 MB total

  // 1) converts (2 launches)
  convert_x<<<2048, 256, 0, stream>>>(x, xb, BB * SS * DD / 4);
  convert_w<<<3 * DD * DD / 4 / 256, 256, 0, stream>>>(wq, wk, wv, wcat);
  // 2) Q/K/V projections (one fused GEMM)
  proj_gemm<<<dim3(24, 64), 256, 0, stream>>>(xb, wcat, q, kk, vv);
  // 3) layout transposes
  k_to_mt<<<dim3(32, 32, 8), dim3(32, 8), 0, stream>>>(kk, mt);
  v_to_vt<<<dim3(64, 32, 4), dim3(32, 8), 0, stream>>>(vv, vt);
  // 4) scores (+ scale 1/1024)
  score_gemm<<<dim3(16, 16, 4), 256, 0, stream>>>(q, mt, sc);
  // 5) softmax (in-place)
  softmax_kernel<<<BB * SS, 256, 0, stream>>>(sc);
  // 6) attn @ V
  pv_gemm<<<dim3(8, 16, 4), 256, 0, stream>>>(sc, vt, out);
}

// Round 4
// 265.170 us; speedup vs baseline: 1.1136x; 1.1136x over previous
//
#include <hip/hip_runtime.h>
#include <hip/hip_bf16.h>
#include <stdint.h>

// Problem: B=4, S=2048, D=1024. fp32 in, fp32 out.
#define BB 4
#define SS 2048
#define DD 1024

typedef __attribute__((ext_vector_type(4))) float f32x4;
typedef __attribute__((ext_vector_type(8))) __bf16 bf16x8;

typedef const __attribute__((address_space(1))) void* gptr_t;
typedef __attribute__((address_space(3))) void* lptr_t;

__device__ __forceinline__ void load_lds16(const void* g, void* l) {
  // async global->LDS, 16B per lane; LDS dest = wave-uniform base + lane*16
  __builtin_amdgcn_global_load_lds((gptr_t)g, (lptr_t)l, 16, 0, 0);
}

#define SBAR0() __builtin_amdgcn_sched_barrier(0)

template <int N>
__device__ __forceinline__ void wait_vmcnt() {
  if constexpr (N == 0) asm volatile("s_waitcnt vmcnt(0)" ::: "memory");
  else if constexpr (N == 6) asm volatile("s_waitcnt vmcnt(6)" ::: "memory");
  else if constexpr (N == 8) asm volatile("s_waitcnt vmcnt(8)" ::: "memory");
}
__device__ __forceinline__ void wait_lgkm0() {
  asm volatile("s_waitcnt lgkmcnt(0)" ::: "memory");
}

__device__ __forceinline__ unsigned short f2bf(float x) {
  union { float f; uint32_t u; } v; v.f = x;
  uint32_t u = v.u;
  return (unsigned short)((u + 0x7FFFu + ((u >> 16) & 1u)) >> 16); // RNE
}
__device__ __forceinline__ float bf2f(unsigned short h) {
  union { uint32_t u; float f; } v; v.u = ((uint32_t)h) << 16; return v.f;
}

// ---------------- fp32 -> bf16 convert: x (grid-stride) ----------------
__global__ __launch_bounds__(256) void convert_x(
    const float* __restrict__ in, unsigned short* __restrict__ out, int n4) {
  for (int i = blockIdx.x * 256 + threadIdx.x; i < n4; i += gridDim.x * 256) {
    float4 v = ((const float4*)in)[i];
    ushort4 o;
    o.x = f2bf(v.x); o.y = f2bf(v.y); o.z = f2bf(v.z); o.w = f2bf(v.w);
    ((ushort4*)out)[i] = o;
  }
}

// ---------------- fp32 -> bf16 convert: the 3 weight matrices ----------------
__global__ __launch_bounds__(256) void convert_w(
    const float* __restrict__ wq, const float* __restrict__ wk,
    const float* __restrict__ wv, unsigned short* __restrict__ wcat) {
  const int n4 = DD * DD / 4;  // per matrix
  int i = blockIdx.x * 256 + threadIdx.x;  // 0 .. 3*n4-1
  const int which = i / n4, j = i - which * n4;
  const float* src = (which == 0) ? wq : ((which == 1) ? wk : wv);
  float4 v = ((const float4*)src)[j];
  ushort4 o;
  o.x = f2bf(v.x); o.y = f2bf(v.y); o.z = f2bf(v.z); o.w = f2bf(v.w);
  ((ushort4*)(wcat + (size_t)which * DD * DD))[j] = o;
}

// =================== 256-wide deep-pipelined GEMM core =====================
// C[BM x 256] = A[M,K] @ Bt[256-col panel of N,K]^T, bf16 MFMA 16x16x32.
// 512 threads = 8 waves (2 x 4). BK=64, double-buffered LDS, counted vmcnt
// (never 0 in steady state), T2 XOR swizzle (phys col16 = logical ^ (row&7))
// applied BOTH sides: pre-swizzled global source for global_load_lds (linear
// LDS dest) + swizzled ds_read addresses (rule #21).
template <int BM, int KLEN>
__device__ __forceinline__ void gemm_core(
    const unsigned short* __restrict__ A, const unsigned short* __restrict__ Bt,
    int lda, int ldb, int row0, int col0, char* lds,
    f32x4 (&acc)[BM / 32][4]) {
  constexpr int M_REP = BM / 32;            // M fragments per wave
  constexpr int NT   = KLEN / 64;           // K tiles
  constexpr int ASZ  = BM * 128;            // A tile bytes (BM x 64 x 2B)
  constexpr int BUFSZ = ASZ + 32768;        // + B tile (256 x 64 x 2B)
  constexpr int LPT  = (BM + 256) / 64;     // gload_lds per wave per K-tile
  constexpr int NA   = BM / 64;             // A chunks (1KB) per wave

  const int tid  = threadIdx.x;
  const int lane = tid & 63;
  const int w    = tid >> 6;                // 0..7
  const int wr = w >> 2, wc = w & 3;        // 2 x 4 wave grid

#pragma unroll
  for (int f = 0; f < M_REP; ++f)
#pragma unroll
    for (int n = 0; n < 4; ++n) acc[f][n] = (f32x4)(0.f);

  // ---- stage-side addressing (per lane; source pre-swizzle) ----
  const int l8 = lane >> 3, l7 = lane & 7;
  const int swz = l7 ^ l8;                  // logical col16 this lane fetches
  const unsigned short* srcA = A  + (size_t)(row0 + w * (BM / 8) + l8) * lda + swz * 8;
  const unsigned short* srcB = Bt + (size_t)(col0 + w * 32 + l8) * ldb + swz * 8;
  char* ldsAw = lds + w * (BM / 8) * 128;   // wave's A rows
  char* ldsBw = lds + ASZ + w * 4096;       // wave's B rows

  // ---- read-side addressing (swizzled) ----
  const int l15 = lane & 15, l16 = lane >> 4;
  const int xc0 = ((l16) ^ l7) * 16;        // k-substep 0 (row&7 == l7 always)
  const int xc1 = ((4 + l16) ^ l7) * 16;    // k-substep 1
  const char* rdA = lds + wr * (BM / 2) * 128 + l15 * 128;
  const char* rdB = lds + ASZ + wc * 8192 + l15 * 128;

  auto STAGE = [&](int kt) {
    const unsigned short* a = srcA + kt * 64;
    const unsigned short* b = srcB + kt * 64;
    char* la = ldsAw + (kt & 1) * BUFSZ;
    char* lb = ldsBw + (kt & 1) * BUFSZ;
#pragma unroll
    for (int c = 0; c < NA; ++c) load_lds16(a + (size_t)c * 8 * lda, la + c * 1024);
#pragma unroll
    for (int c = 0; c < 4; ++c)  load_lds16(b + (size_t)c * 8 * ldb, lb + c * 1024);
  };

  STAGE(0);
  STAGE(1);

#pragma unroll 1
  for (int t = 0; t < NT; ++t) {
    // tile t's loads retired (mine); barrier makes it true block-wide
    if (t == NT - 1) wait_vmcnt<0>(); else wait_vmcnt<LPT>();
    SBAR0();
    __builtin_amdgcn_s_barrier();
    SBAR0();

    const char* pA = rdA + (t & 1) * BUFSZ;
    const char* pB = rdB + (t & 1) * BUFSZ;

    bf16x8 a0[M_REP], b0[4], a1[M_REP], b1[4];
#pragma unroll
    for (int n = 0; n < 4; ++n) b0[n] = *(const bf16x8*)(pB + xc0 + n * 2048);
#pragma unroll
    for (int f = 0; f < M_REP; ++f) a0[f] = *(const bf16x8*)(pA + xc0 + f * 2048);

    __builtin_amdgcn_s_setprio(1);
#pragma unroll
    for (int f = 0; f < M_REP; ++f)
#pragma unroll
      for (int n = 0; n < 4; ++n)
        acc[f][n] = __builtin_amdgcn_mfma_f32_16x16x32_bf16(a0[f], b0[n], acc[f][n], 0, 0, 0);
    __builtin_amdgcn_s_setprio(0);

#pragma unroll
    for (int n = 0; n < 4; ++n) b1[n] = *(const bf16x8*)(pB + xc1 + n * 2048);
#pragma unroll
    for (int f = 0; f < M_REP; ++f) a1[f] = *(const bf16x8*)(pA + xc1 + f * 2048);

    wait_lgkm0();   // ALL my ds_reads of buf[t&1] retired
    SBAR0();
    __builtin_amdgcn_s_barrier();   // every wave done reading buf[t&1]
    SBAR0();
    if (t + 2 < NT) STAGE(t + 2);   // refill freed buffer; stays in flight

    __builtin_amdgcn_s_setprio(1);
#pragma unroll
    for (int f = 0; f < M_REP; ++f)
#pragma unroll
      for (int n = 0; n < 4; ++n)
        acc[f][n] = __builtin_amdgcn_mfma_f32_16x16x32_bf16(a1[f], b1[n], acc[f][n], 0, 0, 0);
    __builtin_amdgcn_s_setprio(0);
  }
}

// ---------------- projection GEMM: [8192,1024] @ Wcat[3072,1024]^T ----------
// BM=128, BN=256: grid 12 x 64 = 768 blocks (3 exact GPU rounds).
__global__ __launch_bounds__(512, 2) void proj_gemm(
    const unsigned short* __restrict__ xb, const unsigned short* __restrict__ wcat,
    unsigned short* __restrict__ q, unsigned short* __restrict__ kk,
    unsigned short* __restrict__ vv) {
  extern __shared__ char lds[];
  f32x4 acc[4][4];
  const int bn = blockIdx.x, bm = blockIdx.y;
  gemm_core<128, 1024>(xb, wcat, 1024, 1024, bm * 128, bn * 256, lds, acc);

  const int lane = threadIdx.x & 63, w = threadIdx.x >> 6;
  const int wr = w >> 2, wc = w & 3;
  const int which = bn >> 2;  // 0:q 1:k 2:v (256-col tile within one 1024 output)
  unsigned short* dst = (which == 0) ? q : ((which == 1) ? kk : vv);
  const int colb = (bn & 3) * 256 + wc * 64 + (lane & 15);
  const int rowb = bm * 128 + wr * 64 + (lane >> 4) * 4;
#pragma unroll
  for (int f = 0; f < 4; ++f)
#pragma unroll
    for (int i = 0; i < 4; ++i) {
      const size_t rowoff = (size_t)(rowb + f * 16 + i) * 1024;
#pragma unroll
      for (int n = 0; n < 4; ++n)
        dst[rowoff + colb + n * 16] = f2bf(acc[f][n][i]);
    }
}

// ---------------- K -> Mt (reshape folded transpose) ----------------
// Mt[b][delta*1024 + j][i] = K[b][2i+delta][j]
__global__ __launch_bounds__(256) void k_to_mt(
    const unsigned short* __restrict__ k, unsigned short* __restrict__ mt) {
  const int z = blockIdx.z, b = z >> 1, delta = z & 1;
  const unsigned short* kb = k + (size_t)b * SS * DD + (size_t)delta * DD;  // ld=2048
  unsigned short* mtb = mt + (size_t)b * SS * DD + (size_t)delta * DD * DD; // [1024][1024]
  __shared__ unsigned short tile[32][33];
  const int tx = threadIdx.x, ty = threadIdx.y;
  const int i0 = blockIdx.x * 32, j0 = blockIdx.y * 32;
#pragma unroll
  for (int yy = ty; yy < 32; yy += 8)
    tile[yy][tx] = kb[(size_t)(i0 + yy) * 2048 + j0 + tx];
  __syncthreads();
#pragma unroll
  for (int yy = ty; yy < 32; yy += 8)
    mtb[(size_t)(j0 + yy) * 1024 + i0 + tx] = tile[tx][yy];
}

// ---------------- V -> Vt ----------------
__global__ __launch_bounds__(256) void v_to_vt(
    const unsigned short* __restrict__ v, unsigned short* __restrict__ vt) {
  const int b = blockIdx.z;
  const unsigned short* vb = v + (size_t)b * SS * DD;   // V[k][n], ld=1024
  unsigned short* vtb = vt + (size_t)b * DD * SS;       // Vt[n][k], ld=2048
  __shared__ unsigned short tile[32][33];
  const int tx = threadIdx.x, ty = threadIdx.y;
  const int k0 = blockIdx.x * 32, n0 = blockIdx.y * 32;
#pragma unroll
  for (int yy = ty; yy < 32; yy += 8)
    tile[yy][tx] = vb[(size_t)(k0 + yy) * 1024 + n0 + tx];
  __syncthreads();
#pragma unroll
  for (int yy = ty; yy < 32; yy += 8)
    vtb[(size_t)(n0 + yy) * 2048 + k0 + tx] = tile[tx][yy];
}

// ---------------- scores GEMM: Q[2048,1024] @ Mt[2048,1024]^T (x 1/1024) ----
// BM=256: grid 8 x 8 x 4 = 256 blocks (1 exact GPU round).
__global__ __launch_bounds__(512, 2) void score_gemm(
    const unsigned short* __restrict__ q, const unsigned short* __restrict__ mt,
    unsigned short* __restrict__ sc) {
  extern __shared__ char lds[];
  f32x4 acc[8][4];
  const int b = blockIdx.z;
  gemm_core<256, 1024>(q + (size_t)b * SS * DD, mt + (size_t)b * SS * DD,
                       1024, 1024, blockIdx.y * 256, blockIdx.x * 256, lds, acc);
  unsigned short* out = sc + (size_t)b * SS * SS;
  const int lane = threadIdx.x & 63, w = threadIdx.x >> 6;
  const int wr = w >> 2, wc = w & 3;
  const int colb = blockIdx.x * 256 + wc * 64 + (lane & 15);
  const int rowb = blockIdx.y * 256 + wr * 128 + (lane >> 4) * 4;
  const float scale = 1.0f / 1024.0f;
#pragma unroll
  for (int f = 0; f < 8; ++f)
#pragma unroll
    for (int i = 0; i < 4; ++i) {
      const size_t rowoff = (size_t)(rowb + f * 16 + i) * 2048;
#pragma unroll
      for (int n = 0; n < 4; ++n)
        out[rowoff + colb + n * 16] = f2bf(acc[f][n][i] * scale);
    }
}

// ---------------- row softmax IN-PLACE: bf16 [8192][2048] ----------------
__global__ __launch_bounds__(256) void softmax_kernel(unsigned short* __restrict__ sc) {
  const size_t row = blockIdx.x;
  unsigned short* io = sc + row * 2048;
  const int t = threadIdx.x;
  ushort4 u0 = ((const ushort4*)io)[t];
  ushort4 u1 = ((const ushort4*)io)[t + 256];
  float v[8];
  v[0] = bf2f(u0.x); v[1] = bf2f(u0.y); v[2] = bf2f(u0.z); v[3] = bf2f(u0.w);
  v[4] = bf2f(u1.x); v[5] = bf2f(u1.y); v[6] = bf2f(u1.z); v[7] = bf2f(u1.w);
  float m = v[0];
#pragma unroll
  for (int j = 1; j < 8; ++j) m = fmaxf(m, v[j]);
#pragma unroll
  for (int off = 32; off > 0; off >>= 1) m = fmaxf(m, __shfl_xor(m, off));
  __shared__ float redm[4], reds[4];
  const int w = t >> 6;
  if ((t & 63) == 0) redm[w] = m;
  __syncthreads();
  m = fmaxf(fmaxf(redm[0], redm[1]), fmaxf(redm[2], redm[3]));
  float s = 0.f;
#pragma unroll
  for (int j = 0; j < 8; ++j) { v[j] = __expf(v[j] - m); s += v[j]; }
#pragma unroll
  for (int off = 32; off > 0; off >>= 1) s += __shfl_xor(s, off);
  if ((t & 63) == 0) reds[w] = s;
  __syncthreads();
  const float inv = 1.0f / (reds[0] + reds[1] + reds[2] + reds[3]);
  ushort4 o0, o1;
  o0.x = f2bf(v[0] * inv); o0.y = f2bf(v[1] * inv); o0.z = f2bf(v[2] * inv); o0.w = f2bf(v[3] * inv);
  o1.x = f2bf(v[4] * inv); o1.y = f2bf(v[5] * inv); o1.z = f2bf(v[6] * inv); o1.w = f2bf(v[7] * inv);
  ((ushort4*)io)[t] = o0;
  ((ushort4*)io)[t + 256] = o1;
}

// ---------------- PV GEMM: P[2048,2048] @ Vt[1024,2048]^T -> fp32 ----------
// BM=128: grid 4 x 16 x 4 = 256 blocks (1 exact GPU round).
__global__ __launch_bounds__(512, 2) void pv_gemm(
    const unsigned short* __restrict__ p, const unsigned short* __restrict__ vt,
    float* __restrict__ out) {
  extern __shared__ char lds[];
  f32x4 acc[4][4];
  const int b = blockIdx.z;
  gemm_core<128, 2048>(p + (size_t)b * SS * SS, vt + (size_t)b * DD * SS,
                       2048, 2048, blockIdx.y * 128, blockIdx.x * 256, lds, acc);
  float* ob = out + (size_t)b * SS * DD;
  const int lane = threadIdx.x & 63, w = threadIdx.x >> 6;
  const int wr = w >> 2, wc = w & 3;
  const int colb = blockIdx.x * 256 + wc * 64 + (lane & 15);
  const int rowb = blockIdx.y * 128 + wr * 64 + (lane >> 4) * 4;
#pragma unroll
  for (int f = 0; f < 4; ++f)
#pragma unroll
    for (int i = 0; i < 4; ++i) {
      const size_t rowoff = (size_t)(rowb + f * 16 + i) * 1024;
#pragma unroll
      for (int n = 0; n < 4; ++n)
        ob[rowoff + colb + n * 16] = acc[f][n][i];
    }
}

extern "C" void kernel_launch(void* const* d_in, const int* in_sizes, int n_in,
                              void* d_out, int out_size, void* d_ws, size_t ws_size,
                              hipStream_t stream) {
  const float* x  = (const float*)d_in[0];
  const float* wq = (const float*)d_in[1];
  const float* wk = (const float*)d_in[2];
  const float* wv = (const float*)d_in[3];
  float* out = (float*)d_out;
  uint8_t* ws = (uint8_t*)d_ws;

  const size_t MB = 1u << 20;
  unsigned short* xb   = (unsigned short*)(ws);               // 16 MB  [8192][1024]
  unsigned short* wcat = (unsigned short*)(ws + 16 * MB);     //  6 MB  [3072][1024]
  unsigned short* q    = (unsigned short*)(ws + 22 * MB);     // 16 MB
  unsigned short* kk   = (unsigned short*)(ws + 38 * MB);     // 16 MB
  unsigned short* vv   = (unsigned short*)(ws + 54 * MB);     // 16 MB
  unsigned short* mt   = (unsigned short*)(ws + 70 * MB);     // 16 MB  [b][2048][1024]
  unsigned short* vt   = (unsigned short*)(ws + 86 * MB);     // 16 MB  [b][1024][2048]
  unsigned short* sc   = (unsigned short*)(ws + 102 * MB);    // 32 MB  [b][2048][2048] (softmax in-place)
                                                              // -> 134 MB total

  convert_x<<<2048, 256, 0, stream>>>(x, xb, BB * SS * DD / 4);
  convert_w<<<3 * DD * DD / 4 / 256, 256, 0, stream>>>(wq, wk, wv, wcat);
  proj_gemm<<<dim3(12, 64), 512, 96 * 1024, stream>>>(xb, wcat, q, kk, vv);
  k_to_mt<<<dim3(32, 32, 8), dim3(32, 8), 0, stream>>>(kk, mt);
  v_to_vt<<<dim3(64, 32, 4), dim3(32, 8), 0, stream>>>(vv, vt);
  score_gemm<<<dim3(8, 8, 4), 512, 128 * 1024, stream>>>(q, mt, sc);
  softmax_kernel<<<BB * SS, 256, 0, stream>>>(sc);
  pv_gemm<<<dim3(4, 16, 4), 512, 96 * 1024, stream>>>(sc, vt, out);
}